// Round 5
// baseline (517.366 us; speedup 1.0000x reference)
//
#include <hip/hip_runtime.h>
#include <hip/hip_bf16.h>
#include <stdint.h>

// Problem constants (B=4096, V=512, H=64)
#define BB 4096
#define VV 512
#define HH 64

typedef short bf16x8 __attribute__((ext_vector_type(8)));
typedef float floatx4 __attribute__((ext_vector_type(4)));
typedef unsigned short ushort8 __attribute__((ext_vector_type(8)));

typedef const __attribute__((address_space(1))) void g_void;
typedef __attribute__((address_space(3))) void l_void;

__device__ __forceinline__ void gload_lds16(const void* g, void* l) {
    __builtin_amdgcn_global_load_lds((g_void*)g, (l_void*)l, 16, 0, 0);
}

__device__ __forceinline__ unsigned short f2bf_rne(float f) {
    unsigned int u = __float_as_uint(f);
    u += 0x7FFFu + ((u >> 16) & 1u);   // round-to-nearest-even
    return (unsigned short)(u >> 16);
}

// ---------------------------------------------------------------- adj only
__global__ __launch_bounds__(256) void adj_kernel(const float* __restrict__ logits,
                                                  float* __restrict__ adj_out) {
    int idx = blockIdx.x * 256 + threadIdx.x;
    int v = idx >> 9, u = idx & (VV - 1);
    adj_out[idx] = (logits[idx] > 0.0f && v != u) ? 1.0f : 0.0f;
}

// ---------------------------------------------------------------- fused prep
// blocks [0, 4096): W1[i][v][h]*adj[v,i] -> bf16 W1t[i][h][v]  (B^T layout)
// blocks [4096, 5120): adj output + X -> packed bf16 Xp
// Xp layout: [rb][ks][mt][lane][8]; lane=quad*16+ln holds
// X[rb*64+mt*16+ln][ks*32+quad*8..+7] => A-frag loads are coalesced 1 KB.
__global__ __launch_bounds__(256) void prep_fused_kernel(
        const float* __restrict__ X, const float* __restrict__ logits,
        const float* __restrict__ W1, float* __restrict__ adj_out,
        unsigned short* __restrict__ Xp, unsigned short* __restrict__ W1t) {
    __shared__ float tile[64][65];
    __shared__ float maskv[64];
    int bx = blockIdx.x;
    int t  = threadIdx.x;
    if (bx < 4096) {
        int i  = bx >> 3;
        int v0 = (bx & 7) << 6;
        if (t < 64) {
            int v = v0 + t;
            maskv[t] = (logits[(size_t)v * VV + i] > 0.0f && v != i) ? 1.0f : 0.0f;
        }
        const float* src = W1 + ((size_t)i * VV + v0) * HH;
        #pragma unroll
        for (int j = 0; j < 16; ++j) {
            int idx = j * 256 + t;
            tile[idx >> 6][idx & 63] = src[idx];
        }
        __syncthreads();
        unsigned short* dst = W1t + (size_t)i * (HH * VV) + v0;
        #pragma unroll
        for (int j = 0; j < 2; ++j) {
            int c = j * 256 + t;
            int h = c >> 3;
            int vr0 = (c & 7) * 8;
            ushort8 o;
            #pragma unroll
            for (int r = 0; r < 8; ++r)
                o[r] = f2bf_rne(tile[vr0 + r][h] * maskv[vr0 + r]);
            *(ushort8*)&dst[(size_t)h * VV + vr0] = o;
        }
    } else {
        int idx = (bx - 4096) * 256 + t;           // [0, 262144)
        {   // adj: sigmoid(x) > 0.5  <=>  x > 0 ; zero diagonal
            int v = idx >> 9, u = idx & (VV - 1);
            adj_out[idx] = (logits[idx] > 0.0f && v != u) ? 1.0f : 0.0f;
        }
        {   // pack chunk idx
            int lane = idx & 63;
            int mt   = (idx >> 6) & 3;
            int ks   = (idx >> 8) & 15;
            int rb   = idx >> 12;
            int row  = rb * 64 + mt * 16 + (lane & 15);
            int k0   = ks * 32 + (lane >> 4) * 8;
            const float* src = X + (size_t)row * VV + k0;
            ushort8 o;
            #pragma unroll
            for (int e = 0; e < 8; ++e) o[e] = f2bf_rne(src[e]);
            *(ushort8*)(Xp + (size_t)idx * 8) = o;
        }
    }
}

// ---------------------------------------------------------------- main GEMM
// PERSISTENT: 256 blocks (1/CU) x 512 threads (8 waves = 2/SIMD).
// Each block runs 16 items = (net i, 512-row chunk). LDS double-buffers two
// 64 KB W1t rows: item n computes from buf[n&1] while streaming item n+1's
// W1t into buf[~n&1] (one 8 KB slice per K-step, steps 0..7). The vmcnt(0)
// drain at the item barrier hits loads issued ~10k cycles earlier -> free.
// XCD-aware schedule: block b -> XCD b&7 owns i in [64*(b&7), +64); at any
// step the 8 blocks sharing a W1t row are on the SAME XCD -> one L2 fetch.
__global__ __launch_bounds__(512, 2) void dag_gemm_kernel(
        const unsigned short* __restrict__ Xp,    // packed A frags
        const unsigned short* __restrict__ W1t,   // [V][H][V] bf16 (masked, B^T)
        const float* __restrict__ b1,             // [V][H]
        const float* __restrict__ W2,             // [V][H]
        const float* __restrict__ b2,             // [V]
        float* __restrict__ outT)                 // [V][B] transposed output
{
    __shared__ __align__(16) unsigned short Ws[2][HH * VV];  // 2 x 64 KB
    __shared__ float Po[512];

    const int t    = threadIdx.x;
    const int wave = t >> 6;
    const int lane = t & 63;
    const int ln   = lane & 15;
    const int quad = lane >> 4;

    const int x = blockIdx.x & 7;      // XCD slot
    const int j = blockIdx.x >> 3;     // 0..31 within XCD

    // ---- stage item 0 into buf 0 (the only exposed staging drain)
    {
        int i0 = x * 64 + (j >> 3);
        const unsigned short* wbase = W1t + (size_t)i0 * (HH * VV);
        #pragma unroll
        for (int c8 = 0; c8 < 8; ++c8) {
            int c = c8 * 512 + t;
            int h = c >> 6, s = c & 63;
            gload_lds16(wbase + (size_t)h * VV + (size_t)(s ^ (h & 7)) * 8,
                        (char*)Ws[0] + c * 16);
        }
    }
    __syncthreads();

    #pragma unroll 1
    for (int n = 0; n < 16; ++n) {
        const int g     = n * 32 + j;
        const int i     = x * 64 + (g >> 3);
        const int chunk = g & 7;
        const int buf   = n & 1;

        const unsigned short* wnext = W1t;   // dummy when n==15
        if (n < 15) {
            int gn = (n + 1) * 32 + j;
            wnext = W1t + (size_t)(x * 64 + (gn >> 3)) * (HH * VV);
        }

        // wave's packed A stream: frag(ks,mt) at +(ks*4+mt)*512
        const unsigned short* abase =
            Xp + (size_t)(chunk * 8 + wave) * (64 * VV) + lane * 8;

        bf16x8 af[4][4];
        #pragma unroll
        for (int s = 0; s < 3; ++s)
            #pragma unroll
            for (int mt = 0; mt < 4; ++mt)
                af[s][mt] = *(const bf16x8*)(abase + (s * 4 + mt) * 512);

        floatx4 acc[4][4];
        #pragma unroll
        for (int a = 0; a < 4; ++a)
            #pragma unroll
            for (int b = 0; b < 4; ++b)
                acc[a][b] = (floatx4){0.f, 0.f, 0.f, 0.f};

        const unsigned short* wsb = Ws[buf];
        bf16x8 bq[2][4];
        #pragma unroll
        for (int nt = 0; nt < 4; ++nt)
            bq[0][nt] = *(const bf16x8*)
                &wsb[(nt * 16 + ln) * VV + (quad ^ (ln & 7)) * 8];

        #pragma unroll
        for (int kk = 0; kk < 16; ++kk) {
            // stream next item's W1t: one 8 KB slice per step, steps 0..7
            if (kk < 8 && n < 15) {
                int c = kk * 512 + t;
                int h = c >> 6, s = c & 63;
                gload_lds16(wnext + (size_t)h * VV + (size_t)(s ^ (h & 7)) * 8,
                            (char*)Ws[buf ^ 1] + c * 16);
            }
            // depth-3 A prefetch
            if (kk < 13) {
                #pragma unroll
                for (int mt = 0; mt < 4; ++mt)
                    af[(kk + 3) & 3][mt] =
                        *(const bf16x8*)(abase + ((kk + 3) * 4 + mt) * 512);
            }
            // B prefetch (LDS)
            if (kk < 15) {
                #pragma unroll
                for (int nt = 0; nt < 4; ++nt)
                    bq[(kk + 1) & 1][nt] = *(const bf16x8*)
                        &wsb[(nt * 16 + ln) * VV +
                             (((kk + 1) * 4 + quad) ^ (ln & 7)) * 8];
            }
            #pragma unroll
            for (int mt = 0; mt < 4; ++mt)
                #pragma unroll
                for (int nt = 0; nt < 4; ++nt)
                    acc[mt][nt] = __builtin_amdgcn_mfma_f32_16x16x32_bf16(
                        af[kk & 3][mt], bq[kk & 1][nt], acc[mt][nt], 0, 0, 0);
        }

        // ---- fused epilogue: relu(acc + b1) . W2 + b2 (fp32)
        float b1v[4], w2v[4];
        #pragma unroll
        for (int nt = 0; nt < 4; ++nt) {
            b1v[nt] = b1[i * HH + nt * 16 + ln];
            w2v[nt] = W2[i * HH + nt * 16 + ln];
        }
        const float b2i = b2[i];
        #pragma unroll
        for (int mt = 0; mt < 4; ++mt) {
            #pragma unroll
            for (int r = 0; r < 4; ++r) {
                float p = 0.f;
                #pragma unroll
                for (int nt = 0; nt < 4; ++nt) {
                    float hv = acc[mt][nt][r] + b1v[nt];  // row=quad*4+r, col=nt*16+ln
                    hv = hv > 0.f ? hv : 0.f;
                    p += hv * w2v[nt];
                }
                p += __shfl_xor(p, 8);
                p += __shfl_xor(p, 4);
                p += __shfl_xor(p, 2);
                p += __shfl_xor(p, 1);
                if (ln == 0)
                    Po[wave * 64 + mt * 16 + quad * 4 + r] = p + b2i;  // intra-wave
            }
        }
        // coalesced 2 KB store; Po[t] was written by this thread's own wave
        // (same-wave LDS ops are ordered). Store drains at the NEXT barrier.
        outT[(size_t)i * BB + chunk * 512 + t] = Po[t];
        __syncthreads();   // buf[n&1] reads done; staging for n+1 long complete
    }
}

// ------------------------------------------- outT[V][B] -> out[B][V] transpose
__global__ __launch_bounds__(256) void transpose_kernel(const float* __restrict__ outT,
                                                        float* __restrict__ out) {
    __shared__ float tile[64][65];
    int i0 = (blockIdx.x & 7) * 64;
    int r0 = (blockIdx.x >> 3) * 64;
    int t  = threadIdx.x;
    #pragma unroll
    for (int j = 0; j < 16; ++j) {
        int idx = j * 256 + t;
        int ii = idx >> 6, rr = idx & 63;
        tile[ii][rr] = outT[(size_t)(i0 + ii) * BB + r0 + rr];
    }
    __syncthreads();
    #pragma unroll
    for (int j = 0; j < 16; ++j) {
        int idx = j * 256 + t;
        int rr = idx >> 6, ii = idx & 63;
        out[(size_t)(r0 + rr) * VV + i0 + ii] = tile[ii][rr];
    }
}

// ----------------------------- fallback (no workspace): fp32 vector path
__global__ __launch_bounds__(256) void fallback_kernel(
        const float* __restrict__ X, const float* __restrict__ logits,
        const float* __restrict__ W1, const float* __restrict__ b1,
        const float* __restrict__ W2, const float* __restrict__ b2,
        float* __restrict__ out) {
    __shared__ float Wc[128][64];
    int i   = blockIdx.x & (VV - 1);
    int row = (blockIdx.x >> 9) * 256 + threadIdx.x;
    float acc[64];
    #pragma unroll
    for (int h = 0; h < 64; ++h) acc[h] = 0.f;
    for (int v0 = 0; v0 < VV; v0 += 128) {
        __syncthreads();
        for (int j = 0; j < 32; ++j) {
            int idx = j * 256 + threadIdx.x;
            int vr = idx >> 6, h = idx & 63;
            int v = v0 + vr;
            float m = (logits[(size_t)v * VV + i] > 0.f && v != i) ? 1.f : 0.f;
            Wc[vr][h] = W1[((size_t)i * VV + v) * HH + h] * m;
        }
        __syncthreads();
        for (int vr = 0; vr < 128; ++vr) {
            float xv = X[(size_t)row * VV + v0 + vr];
            #pragma unroll
            for (int h = 0; h < 64; ++h) acc[h] += xv * Wc[vr][h];
        }
    }
    float p = b2[i];
    #pragma unroll
    for (int h = 0; h < 64; ++h) {
        float hv = acc[h] + b1[i * HH + h];
        p += (hv > 0.f ? hv : 0.f) * W2[i * HH + h];
    }
    out[(size_t)row * VV + i] = p;
}

extern "C" void kernel_launch(void* const* d_in, const int* in_sizes, int n_in,
                              void* d_out, int out_size, void* d_ws, size_t ws_size,
                              hipStream_t stream) {
    const float* X      = (const float*)d_in[0];
    const float* logits = (const float*)d_in[1];
    const float* W1     = (const float*)d_in[2];
    const float* b1     = (const float*)d_in[3];
    const float* W2     = (const float*)d_in[4];
    const float* b2     = (const float*)d_in[5];

    float* out     = (float*)d_out;                       // reconstructed [B][V]
    float* adj_out = out + (size_t)BB * VV;               // adj [V][V]

    const size_t xp_bytes   = (size_t)BB * VV * 2;        // 4 MB
    const size_t w1t_bytes  = (size_t)VV * HH * VV * 2;   // 32 MB
    const size_t outt_bytes = (size_t)BB * VV * 4;        // 8 MB
    const size_t need = xp_bytes + w1t_bytes + outt_bytes;

    if (ws_size >= need) {
        unsigned short* Xp   = (unsigned short*)d_ws;
        unsigned short* W1t  = (unsigned short*)((char*)d_ws + xp_bytes);
        float*          outT = (float*)((char*)d_ws + xp_bytes + w1t_bytes);
        hipLaunchKernelGGL(prep_fused_kernel, dim3(5120), dim3(256), 0, stream,
                           X, logits, W1, adj_out, Xp, W1t);
        hipLaunchKernelGGL(dag_gemm_kernel, dim3(256), dim3(512), 0, stream,
                           Xp, W1t, b1, W2, b2, outT);
        hipLaunchKernelGGL(transpose_kernel, dim3((BB / 64) * (VV / 64)), dim3(256), 0, stream,
                           outT, out);
    } else {
        hipLaunchKernelGGL(adj_kernel, dim3((VV * VV) / 256), dim3(256), 0, stream,
                           logits, adj_out);
        hipLaunchKernelGGL(fallback_kernel, dim3(VV * (BB / 256)), dim3(256), 0, stream,
                           X, logits, W1, b1, W2, b2, out);
    }
}

// Round 6
// 516.422 us; speedup vs baseline: 1.0018x; 1.0018x over previous
//
#include <hip/hip_runtime.h>
#include <hip/hip_bf16.h>
#include <stdint.h>

// Problem constants (B=4096, V=512, H=64)
#define BB 4096
#define VV 512
#define HH 64

typedef short bf16x8 __attribute__((ext_vector_type(8)));
typedef float floatx4 __attribute__((ext_vector_type(4)));
typedef unsigned short ushort8 __attribute__((ext_vector_type(8)));

typedef const __attribute__((address_space(1))) void g_void;
typedef __attribute__((address_space(3))) void l_void;

__device__ __forceinline__ void gload_lds16(const void* g, void* l) {
    __builtin_amdgcn_global_load_lds((g_void*)g, (l_void*)l, 16, 0, 0);
}

__device__ __forceinline__ unsigned short f2bf_rne(float f) {
    unsigned int u = __float_as_uint(f);
    u += 0x7FFFu + ((u >> 16) & 1u);   // round-to-nearest-even
    return (unsigned short)(u >> 16);
}

// ---------------------------------------------------------------- adj only
__global__ __launch_bounds__(256) void adj_kernel(const float* __restrict__ logits,
                                                  float* __restrict__ adj_out) {
    int idx = blockIdx.x * 256 + threadIdx.x;
    int v = idx >> 9, u = idx & (VV - 1);
    adj_out[idx] = (logits[idx] > 0.0f && v != u) ? 1.0f : 0.0f;
}

// ---------------------------------------------------------------- fused prep
// blocks [0, 4096): W1[i][v][h]*adj[v,i] -> bf16 W1t[i][h][v]  (B^T layout)
// blocks [4096, 5120): adj output + X -> packed bf16 Xp
// Xp layout: [rb][ks][mt][lane][8]; lane=quad*16+ln holds
// X[rb*64+mt*16+ln][ks*32+quad*8..+7] => A-frag loads are coalesced 1 KB.
__global__ __launch_bounds__(256) void prep_fused_kernel(
        const float* __restrict__ X, const float* __restrict__ logits,
        const float* __restrict__ W1, float* __restrict__ adj_out,
        unsigned short* __restrict__ Xp, unsigned short* __restrict__ W1t) {
    __shared__ float tile[64][65];
    __shared__ float maskv[64];
    int bx = blockIdx.x;
    int t  = threadIdx.x;
    if (bx < 4096) {
        int i  = bx >> 3;
        int v0 = (bx & 7) << 6;
        if (t < 64) {
            int v = v0 + t;
            maskv[t] = (logits[(size_t)v * VV + i] > 0.0f && v != i) ? 1.0f : 0.0f;
        }
        const float* src = W1 + ((size_t)i * VV + v0) * HH;
        #pragma unroll
        for (int j = 0; j < 16; ++j) {
            int idx = j * 256 + t;
            tile[idx >> 6][idx & 63] = src[idx];
        }
        __syncthreads();
        unsigned short* dst = W1t + (size_t)i * (HH * VV) + v0;
        #pragma unroll
        for (int j = 0; j < 2; ++j) {
            int c = j * 256 + t;
            int h = c >> 3;
            int vr0 = (c & 7) * 8;
            ushort8 o;
            #pragma unroll
            for (int r = 0; r < 8; ++r)
                o[r] = f2bf_rne(tile[vr0 + r][h] * maskv[vr0 + r]);
            *(ushort8*)&dst[(size_t)h * VV + vr0] = o;
        }
    } else {
        int idx = (bx - 4096) * 256 + t;           // [0, 262144)
        {   // adj: sigmoid(x) > 0.5  <=>  x > 0 ; zero diagonal
            int v = idx >> 9, u = idx & (VV - 1);
            adj_out[idx] = (logits[idx] > 0.0f && v != u) ? 1.0f : 0.0f;
        }
        {   // pack chunk idx
            int lane = idx & 63;
            int mt   = (idx >> 6) & 3;
            int ks   = (idx >> 8) & 15;
            int rb   = idx >> 12;
            int row  = rb * 64 + mt * 16 + (lane & 15);
            int k0   = ks * 32 + (lane >> 4) * 8;
            const float* src = X + (size_t)row * VV + k0;
            ushort8 o;
            #pragma unroll
            for (int e = 0; e < 8; ++e) o[e] = f2bf_rne(src[e]);
            *(ushort8*)(Xp + (size_t)idx * 8) = o;
        }
    }
}

// ---------------------------------------------------------------- main GEMM
// Block = (net i, 1024 batch rows): ONE 64 KB W1t stage amortized over FOUR
// passes of the proven barrier-free 16-step K-loop (256 rows/pass, 4 waves).
// 2048 blocks, 2 resident/CU (cross-block TLP covers each other's staging).
// XCD partition: block b -> XCD b&7 owns i in [64*(b&7), +64); same-i blocks
// are same-XCD and near-consecutive -> W1t row pulled into ONE XCD's L2 once.
// A-frags: coalesced 1 KB loads from packed Xp, depth-3 register prefetch.
__global__ __launch_bounds__(256, 2) void dag_gemm_kernel(
        const unsigned short* __restrict__ Xp,    // packed A frags
        const unsigned short* __restrict__ W1t,   // [V][H][V] bf16 (masked, B^T)
        const float* __restrict__ b1,             // [V][H]
        const float* __restrict__ W2,             // [V][H]
        const float* __restrict__ b2,             // [V]
        float* __restrict__ outT)                 // [V][B] transposed output
{
    __shared__ __align__(16) unsigned short Ws[HH * VV];   // 64 KB
    __shared__ float Po[256];

    const int t    = threadIdx.x;
    const int wave = t >> 6;
    const int lane = t & 63;
    const int ln   = lane & 15;
    const int quad = lane >> 4;

    const int bx = blockIdx.x;            // 2048 blocks
    const int x  = bx & 7;                // XCD slot
    const int r  = bx >> 3;               // 0..255 within XCD
    const int i  = x * 64 + (r >> 2);     // 4 consecutive-r blocks share i
    const int c4 = r & 3;                 // which 1024-row quarter

    // ---- stage full W1t row i: 4096 chunks of 16B, swizzle sub s -> s^(h&7)
    const unsigned short* wbase = W1t + (size_t)i * (HH * VV);
    #pragma unroll
    for (int j = 0; j < 16; ++j) {
        int c = j * 256 + t;
        int h = c >> 6, s = c & 63;
        gload_lds16(wbase + (size_t)h * VV + (size_t)(s ^ (h & 7)) * 8,
                    (char*)Ws + c * 16);
    }

    // per-block epilogue constants (independent of staging)
    float b1v[4], w2v[4];
    #pragma unroll
    for (int nt = 0; nt < 4; ++nt) {
        b1v[nt] = b1[i * HH + nt * 16 + ln];
        w2v[nt] = W2[i * HH + nt * 16 + ln];
    }
    const float b2i = b2[i];

    __syncthreads();   // drains vmcnt: W1t staged (overlaps co-resident block's K-loop)

    #pragma unroll 1
    for (int pass = 0; pass < 4; ++pass) {
        const int rb0 = c4 * 16 + pass * 4;       // row-block base (row/64)
        // wave's packed A stream: frag(ks,mt) at +(ks*4+mt)*512
        const unsigned short* abase =
            Xp + (size_t)(rb0 + wave) * (64 * VV) + lane * 8;

        bf16x8 af[4][4];
        #pragma unroll
        for (int s = 0; s < 3; ++s)
            #pragma unroll
            for (int mt = 0; mt < 4; ++mt)
                af[s][mt] = *(const bf16x8*)(abase + (s * 4 + mt) * 512);

        floatx4 acc[4][4];
        #pragma unroll
        for (int a = 0; a < 4; ++a)
            #pragma unroll
            for (int b = 0; b < 4; ++b)
                acc[a][b] = (floatx4){0.f, 0.f, 0.f, 0.f};

        bf16x8 bq[2][4];
        #pragma unroll
        for (int nt = 0; nt < 4; ++nt)
            bq[0][nt] = *(const bf16x8*)
                &Ws[(nt * 16 + ln) * VV + (quad ^ (ln & 7)) * 8];

        #pragma unroll
        for (int kk = 0; kk < 16; ++kk) {
            // depth-3 A prefetch into ring buffer (consumed at kk-1: no WAR)
            if (kk < 13) {
                #pragma unroll
                for (int mt = 0; mt < 4; ++mt)
                    af[(kk + 3) & 3][mt] =
                        *(const bf16x8*)(abase + ((kk + 3) * 4 + mt) * 512);
            }
            // B prefetch (LDS, short latency)
            if (kk < 15) {
                #pragma unroll
                for (int nt = 0; nt < 4; ++nt)
                    bq[(kk + 1) & 1][nt] = *(const bf16x8*)
                        &Ws[(nt * 16 + ln) * VV +
                            (((kk + 1) * 4 + quad) ^ (ln & 7)) * 8];
            }
            #pragma unroll
            for (int mt = 0; mt < 4; ++mt)
                #pragma unroll
                for (int nt = 0; nt < 4; ++nt)
                    acc[mt][nt] = __builtin_amdgcn_mfma_f32_16x16x32_bf16(
                        af[kk & 3][mt], bq[kk & 1][nt], acc[mt][nt], 0, 0, 0);
        }

        // ---- fused epilogue: relu(acc + b1) . W2 + b2 (fp32)
        #pragma unroll
        for (int mt = 0; mt < 4; ++mt) {
            #pragma unroll
            for (int rr = 0; rr < 4; ++rr) {
                float p = 0.f;
                #pragma unroll
                for (int nt = 0; nt < 4; ++nt) {
                    float hv = acc[mt][nt][rr] + b1v[nt]; // row=quad*4+rr, col=nt*16+ln
                    hv = hv > 0.f ? hv : 0.f;
                    p += hv * w2v[nt];
                }
                p += __shfl_xor(p, 8);
                p += __shfl_xor(p, 4);
                p += __shfl_xor(p, 2);
                p += __shfl_xor(p, 1);
                if (ln == 0)
                    Po[wave * 64 + mt * 16 + quad * 4 + rr] = p + b2i; // intra-wave
            }
        }
        // coalesced 256B-per-wave store; Po[t] written by this thread's own
        // wave (same-wave LDS ops are ordered) -> no barrier needed.
        outT[(size_t)i * BB + rb0 * 64 + wave * 64 + lane] = Po[wave * 64 + lane];
    }
}

// ------------------------------------------- outT[V][B] -> out[B][V] transpose
__global__ __launch_bounds__(256) void transpose_kernel(const float* __restrict__ outT,
                                                        float* __restrict__ out) {
    __shared__ float tile[64][65];
    int i0 = (blockIdx.x & 7) * 64;
    int r0 = (blockIdx.x >> 3) * 64;
    int t  = threadIdx.x;
    #pragma unroll
    for (int j = 0; j < 16; ++j) {
        int idx = j * 256 + t;
        int ii = idx >> 6, rr = idx & 63;
        tile[ii][rr] = outT[(size_t)(i0 + ii) * BB + r0 + rr];
    }
    __syncthreads();
    #pragma unroll
    for (int j = 0; j < 16; ++j) {
        int idx = j * 256 + t;
        int rr = idx >> 6, ii = idx & 63;
        out[(size_t)(r0 + rr) * VV + i0 + ii] = tile[ii][rr];
    }
}

// ----------------------------- fallback (no workspace): fp32 vector path
__global__ __launch_bounds__(256) void fallback_kernel(
        const float* __restrict__ X, const float* __restrict__ logits,
        const float* __restrict__ W1, const float* __restrict__ b1,
        const float* __restrict__ W2, const float* __restrict__ b2,
        float* __restrict__ out) {
    __shared__ float Wc[128][64];
    int i   = blockIdx.x & (VV - 1);
    int row = (blockIdx.x >> 9) * 256 + threadIdx.x;
    float acc[64];
    #pragma unroll
    for (int h = 0; h < 64; ++h) acc[h] = 0.f;
    for (int v0 = 0; v0 < VV; v0 += 128) {
        __syncthreads();
        for (int j = 0; j < 32; ++j) {
            int idx = j * 256 + threadIdx.x;
            int vr = idx >> 6, h = idx & 63;
            int v = v0 + vr;
            float m = (logits[(size_t)v * VV + i] > 0.f && v != i) ? 1.f : 0.f;
            Wc[vr][h] = W1[((size_t)i * VV + v) * HH + h] * m;
        }
        __syncthreads();
        for (int vr = 0; vr < 128; ++vr) {
            float xv = X[(size_t)row * VV + v0 + vr];
            #pragma unroll
            for (int h = 0; h < 64; ++h) acc[h] += xv * Wc[vr][h];
        }
    }
    float p = b2[i];
    #pragma unroll
    for (int h = 0; h < 64; ++h) {
        float hv = acc[h] + b1[i * HH + h];
        p += (hv > 0.f ? hv : 0.f) * W2[i * HH + h];
    }
    out[(size_t)row * VV + i] = p;
}

extern "C" void kernel_launch(void* const* d_in, const int* in_sizes, int n_in,
                              void* d_out, int out_size, void* d_ws, size_t ws_size,
                              hipStream_t stream) {
    const float* X      = (const float*)d_in[0];
    const float* logits = (const float*)d_in[1];
    const float* W1     = (const float*)d_in[2];
    const float* b1     = (const float*)d_in[3];
    const float* W2     = (const float*)d_in[4];
    const float* b2     = (const float*)d_in[5];

    float* out     = (float*)d_out;                       // reconstructed [B][V]
    float* adj_out = out + (size_t)BB * VV;               // adj [V][V]

    const size_t xp_bytes   = (size_t)BB * VV * 2;        // 4 MB
    const size_t w1t_bytes  = (size_t)VV * HH * VV * 2;   // 32 MB
    const size_t outt_bytes = (size_t)BB * VV * 4;        // 8 MB
    const size_t need = xp_bytes + w1t_bytes + outt_bytes;

    if (ws_size >= need) {
        unsigned short* Xp   = (unsigned short*)d_ws;
        unsigned short* W1t  = (unsigned short*)((char*)d_ws + xp_bytes);
        float*          outT = (float*)((char*)d_ws + xp_bytes + w1t_bytes);
        hipLaunchKernelGGL(prep_fused_kernel, dim3(5120), dim3(256), 0, stream,
                           X, logits, W1, adj_out, Xp, W1t);
        hipLaunchKernelGGL(dag_gemm_kernel, dim3(2048), dim3(256), 0, stream,
                           Xp, W1t, b1, W2, b2, outT);
        hipLaunchKernelGGL(transpose_kernel, dim3((BB / 64) * (VV / 64)), dim3(256), 0, stream,
                           outT, out);
    } else {
        hipLaunchKernelGGL(adj_kernel, dim3((VV * VV) / 256), dim3(256), 0, stream,
                           logits, adj_out);
        hipLaunchKernelGGL(fallback_kernel, dim3(VV * (BB / 256)), dim3(256), 0, stream,
                           X, logits, W1, b1, W2, b2, out);
    }
}

// Round 7
// 316.404 us; speedup vs baseline: 1.6351x; 1.6322x over previous
//
#include <hip/hip_runtime.h>
#include <hip/hip_bf16.h>
#include <stdint.h>

// Problem constants (B=4096, V=512, H=64)
#define BB 4096
#define VV 512
#define HH 64

typedef short bf16x8 __attribute__((ext_vector_type(8)));
typedef float floatx4 __attribute__((ext_vector_type(4)));
typedef unsigned short ushort8 __attribute__((ext_vector_type(8)));

typedef const __attribute__((address_space(1))) void g_void;
typedef __attribute__((address_space(3))) void l_void;

__device__ __forceinline__ void gload_lds16(const void* g, void* l) {
    __builtin_amdgcn_global_load_lds((g_void*)g, (l_void*)l, 16, 0, 0);
}

__device__ __forceinline__ unsigned short f2bf_rne(float f) {
    unsigned int u = __float_as_uint(f);
    u += 0x7FFFu + ((u >> 16) & 1u);   // round-to-nearest-even
    return (unsigned short)(u >> 16);
}

// ---------------------------------------------------------------- adj only
__global__ __launch_bounds__(256) void adj_kernel(const float* __restrict__ logits,
                                                  float* __restrict__ adj_out) {
    int idx = blockIdx.x * 256 + threadIdx.x;
    int v = idx >> 9, u = idx & (VV - 1);
    adj_out[idx] = (logits[idx] > 0.0f && v != u) ? 1.0f : 0.0f;
}

// ---------------------------------------------------------------- fused prep
// blocks [0, 4096): W1[i][v][h]*adj[v,i] -> bf16 W1t[i][h][v]  (B^T layout)
// blocks [4096, 5120): adj output + X -> packed bf16 Xp
// Xp layout: [rb][ks][mt][lane][8]; lane=quad*16+ln holds
// X[rb*64+mt*16+ln][ks*32+quad*8..+7] => A-frag loads are coalesced 1 KB.
__global__ __launch_bounds__(256) void prep_fused_kernel(
        const float* __restrict__ X, const float* __restrict__ logits,
        const float* __restrict__ W1, float* __restrict__ adj_out,
        unsigned short* __restrict__ Xp, unsigned short* __restrict__ W1t) {
    __shared__ float tile[64][65];   // stride 65: transpose-read conflict-free
    __shared__ float maskv[64];
    int bx = blockIdx.x;
    int t  = threadIdx.x;
    if (bx < 4096) {
        int i  = bx >> 3;
        int v0 = (bx & 7) << 6;
        if (t < 64) {
            int v = v0 + t;
            maskv[t] = (logits[(size_t)v * VV + i] > 0.0f && v != i) ? 1.0f : 0.0f;
        }
        // float4 global loads (1 KB/wave/instr); scalar LDS writes at stride
        // 65 -> banks (vr + 4*h4 + e) % 32: 2-way, free (m136).
        const float4* src4 = (const float4*)(W1 + ((size_t)i * VV + v0) * HH);
        #pragma unroll
        for (int jj = 0; jj < 4; ++jj) {
            int c  = jj * 256 + t;         // float4 index in [0, 4096)
            int vr = c >> 4, h4 = c & 15;
            float4 w = src4[c];
            tile[vr][h4 * 4 + 0] = w.x;
            tile[vr][h4 * 4 + 1] = w.y;
            tile[vr][h4 * 4 + 2] = w.z;
            tile[vr][h4 * 4 + 3] = w.w;
        }
        __syncthreads();
        unsigned short* dst = W1t + (size_t)i * (HH * VV) + v0;
        #pragma unroll
        for (int j = 0; j < 2; ++j) {
            int c = j * 256 + t;
            int h = c >> 3;
            int vr0 = (c & 7) * 8;
            ushort8 o;
            #pragma unroll
            for (int r = 0; r < 8; ++r)
                o[r] = f2bf_rne(tile[vr0 + r][h] * maskv[vr0 + r]);
            *(ushort8*)&dst[(size_t)h * VV + vr0] = o;
        }
    } else {
        int idx = (bx - 4096) * 256 + t;           // [0, 262144)
        {   // adj: sigmoid(x) > 0.5  <=>  x > 0 ; zero diagonal
            int v = idx >> 9, u = idx & (VV - 1);
            adj_out[idx] = (logits[idx] > 0.0f && v != u) ? 1.0f : 0.0f;
        }
        {   // pack chunk idx (two float4 reads, one 16B store)
            int lane = idx & 63;
            int mt   = (idx >> 6) & 3;
            int ks   = (idx >> 8) & 15;
            int rb   = idx >> 12;
            int row  = rb * 64 + mt * 16 + (lane & 15);
            int k0   = ks * 32 + (lane >> 4) * 8;
            const float4* s4 = (const float4*)(X + (size_t)row * VV + k0);
            float4 a = s4[0], b = s4[1];
            ushort8 o;
            o[0] = f2bf_rne(a.x); o[1] = f2bf_rne(a.y);
            o[2] = f2bf_rne(a.z); o[3] = f2bf_rne(a.w);
            o[4] = f2bf_rne(b.x); o[5] = f2bf_rne(b.y);
            o[6] = f2bf_rne(b.z); o[7] = f2bf_rne(b.w);
            *(ushort8*)(Xp + (size_t)idx * 8) = o;
        }
    }
}

// ---------------------------------------------------------------- main GEMM
// PROVEN single-shot body (182.6 us, VGPR 88, no spill): block = (net i,
// 256 rows), 4 waves x (64x64), W1t row staged to LDS once (XOR-swizzled),
// barrier-free K-loop, depth-3 A register prefetch from packed Xp, fused
// relu/W2 epilogue, coalesced outT store.
// Index remap (only change): x=bx&7 -> XCD slot; same-i blocks stay i-major
// AND land on one XCD (%8 round-robin heuristic) -> no cross-XCD W1t dup.
__global__ __launch_bounds__(256, 2) void dag_gemm_kernel(
        const unsigned short* __restrict__ Xp,    // packed A frags
        const unsigned short* __restrict__ W1t,   // [V][H][V] bf16 (masked, B^T)
        const float* __restrict__ b1,             // [V][H]
        const float* __restrict__ W2,             // [V][H]
        const float* __restrict__ b2,             // [V]
        float* __restrict__ outT)                 // [V][B] transposed output
{
    __shared__ __align__(16) unsigned short Ws[HH * VV];   // 64 KB
    __shared__ float Po[256];                              // epilogue gather

    const int t    = threadIdx.x;
    const int wave = t >> 6;
    const int lane = t & 63;
    const int ln   = lane & 15;
    const int quad = lane >> 4;

    const int bx   = blockIdx.x;          // 8192 blocks
    const int x    = bx & 7;              // XCD slot
    const int m    = bx >> 3;             // 0..1023 within XCD
    const int i    = x * 64 + (m >> 4);   // 16 same-XCD blocks share W1t row i
    const int row0 = (m & 15) << 8;

    // wave's packed A stream: 64 KB contiguous, frag(ks,mt) at +(ks*4+mt)*512
    const unsigned short* abase =
        Xp + (size_t)((row0 >> 6) + wave) * (64 * VV) + lane * 8;

    // ---- issue first 3 K-steps of A prefetch (oldest in vmem queue)
    bf16x8 af[4][4];
    #pragma unroll
    for (int s = 0; s < 3; ++s)
        #pragma unroll
        for (int mt = 0; mt < 4; ++mt)
            af[s][mt] = *(const bf16x8*)(abase + (s * 4 + mt) * 512);

    // ---- stage full W1t row i: 4096 chunks of 16B, swizzle sub s -> s^(h&7)
    const unsigned short* wbase = W1t + (size_t)i * (HH * VV);
    #pragma unroll
    for (int j = 0; j < 16; ++j) {
        int c = j * 256 + t;
        int h = c >> 6, s = c & 63;
        gload_lds16(wbase + (size_t)h * VV + (size_t)(s ^ (h & 7)) * 8,
                    (char*)Ws + c * 16);
    }
    __syncthreads();   // drains vmcnt: staging AND af[0..2] complete here

    floatx4 acc[4][4];
    #pragma unroll
    for (int a = 0; a < 4; ++a)
        #pragma unroll
        for (int b = 0; b < 4; ++b)
            acc[a][b] = (floatx4){0.f, 0.f, 0.f, 0.f};

    bf16x8 bq[2][4];
    #pragma unroll
    for (int nt = 0; nt < 4; ++nt)
        bq[0][nt] = *(const bf16x8*)&Ws[(nt * 16 + ln) * VV + (quad ^ (ln & 7)) * 8];

    #pragma unroll
    for (int kk = 0; kk < 16; ++kk) {
        const int cur = kk & 1, nxt = cur ^ 1;
        // A prefetch for step kk+3 into buffer (kk+3)&3 (consumed at kk-1: no WAR)
        if (kk < 13) {
            #pragma unroll
            for (int mt = 0; mt < 4; ++mt)
                af[(kk + 3) & 3][mt] =
                    *(const bf16x8*)(abase + ((kk + 3) * 4 + mt) * 512);
        }
        // B prefetch for step kk+1 (LDS, short latency)
        if (kk < 15) {
            #pragma unroll
            for (int nt = 0; nt < 4; ++nt)
                bq[nxt][nt] = *(const bf16x8*)
                    &Ws[(nt * 16 + ln) * VV + (((kk + 1) * 4 + quad) ^ (ln & 7)) * 8];
        }
        #pragma unroll
        for (int mt = 0; mt < 4; ++mt)
            #pragma unroll
            for (int nt = 0; nt < 4; ++nt)
                acc[mt][nt] = __builtin_amdgcn_mfma_f32_16x16x32_bf16(
                    af[kk & 3][mt], bq[cur][nt], acc[mt][nt], 0, 0, 0);
    }

    // ---- fused epilogue: relu(acc + b1) . W2 + b2, fp32; gather via LDS,
    //      then coalesced 256B-per-wave stores to outT[i][rows]
    float b1v[4], w2v[4];
    #pragma unroll
    for (int nt = 0; nt < 4; ++nt) {
        b1v[nt] = b1[i * HH + nt * 16 + ln];
        w2v[nt] = W2[i * HH + nt * 16 + ln];
    }
    const float b2i = b2[i];
    #pragma unroll
    for (int mt = 0; mt < 4; ++mt) {
        #pragma unroll
        for (int r = 0; r < 4; ++r) {
            float p = 0.f;
            #pragma unroll
            for (int nt = 0; nt < 4; ++nt) {
                float hv = acc[mt][nt][r] + b1v[nt];   // C/D: row=quad*4+r, col=nt*16+ln
                hv = hv > 0.f ? hv : 0.f;
                p += hv * w2v[nt];
            }
            p += __shfl_xor(p, 8);
            p += __shfl_xor(p, 4);
            p += __shfl_xor(p, 2);
            p += __shfl_xor(p, 1);
            if (ln == 0)
                Po[wave * 64 + mt * 16 + quad * 4 + r] = p + b2i;
        }
    }
    __syncthreads();
    outT[(size_t)i * BB + row0 + wave * 64 + lane] = Po[wave * 64 + lane];
}

// ------------------------------------------- outT[V][B] -> out[B][V] transpose
__global__ __launch_bounds__(256) void transpose_kernel(const float* __restrict__ outT,
                                                        float* __restrict__ out) {
    __shared__ float tile[64][65];
    int i0 = (blockIdx.x & 7) * 64;
    int r0 = (blockIdx.x >> 3) * 64;
    int t  = threadIdx.x;
    #pragma unroll
    for (int j = 0; j < 16; ++j) {
        int idx = j * 256 + t;
        int ii = idx >> 6, rr = idx & 63;
        tile[ii][rr] = outT[(size_t)(i0 + ii) * BB + r0 + rr];
    }
    __syncthreads();
    #pragma unroll
    for (int j = 0; j < 16; ++j) {
        int idx = j * 256 + t;
        int rr = idx >> 6, ii = idx & 63;
        out[(size_t)(r0 + rr) * VV + i0 + ii] = tile[ii][rr];
    }
}

// ----------------------------- fallback (no workspace): fp32 vector path
__global__ __launch_bounds__(256) void fallback_kernel(
        const float* __restrict__ X, const float* __restrict__ logits,
        const float* __restrict__ W1, const float* __restrict__ b1,
        const float* __restrict__ W2, const float* __restrict__ b2,
        float* __restrict__ out) {
    __shared__ float Wc[128][64];
    int i   = blockIdx.x & (VV - 1);
    int row = (blockIdx.x >> 9) * 256 + threadIdx.x;
    float acc[64];
    #pragma unroll
    for (int h = 0; h < 64; ++h) acc[h] = 0.f;
    for (int v0 = 0; v0 < VV; v0 += 128) {
        __syncthreads();
        for (int j = 0; j < 32; ++j) {
            int idx = j * 256 + threadIdx.x;
            int vr = idx >> 6, h = idx & 63;
            int v = v0 + vr;
            float m = (logits[(size_t)v * VV + i] > 0.f && v != i) ? 1.f : 0.f;
            Wc[vr][h] = W1[((size_t)i * VV + v) * HH + h] * m;
        }
        __syncthreads();
        for (int vr = 0; vr < 128; ++vr) {
            float xv = X[(size_t)row * VV + v0 + vr];
            #pragma unroll
            for (int h = 0; h < 64; ++h) acc[h] += xv * Wc[vr][h];
        }
    }
    float p = b2[i];
    #pragma unroll
    for (int h = 0; h < 64; ++h) {
        float hv = acc[h] + b1[i * HH + h];
        p += (hv > 0.f ? hv : 0.f) * W2[i * HH + h];
    }
    out[(size_t)row * VV + i] = p;
}

extern "C" void kernel_launch(void* const* d_in, const int* in_sizes, int n_in,
                              void* d_out, int out_size, void* d_ws, size_t ws_size,
                              hipStream_t stream) {
    const float* X      = (const float*)d_in[0];
    const float* logits = (const float*)d_in[1];
    const float* W1     = (const float*)d_in[2];
    const float* b1     = (const float*)d_in[3];
    const float* W2     = (const float*)d_in[4];
    const float* b2     = (const float*)d_in[5];

    float* out     = (float*)d_out;                       // reconstructed [B][V]
    float* adj_out = out + (size_t)BB * VV;               // adj [V][V]

    const size_t xp_bytes   = (size_t)BB * VV * 2;        // 4 MB
    const size_t w1t_bytes  = (size_t)VV * HH * VV * 2;   // 32 MB
    const size_t outt_bytes = (size_t)BB * VV * 4;        // 8 MB
    const size_t need = xp_bytes + w1t_bytes + outt_bytes;

    if (ws_size >= need) {
        unsigned short* Xp   = (unsigned short*)d_ws;
        unsigned short* W1t  = (unsigned short*)((char*)d_ws + xp_bytes);
        float*          outT = (float*)((char*)d_ws + xp_bytes + w1t_bytes);
        hipLaunchKernelGGL(prep_fused_kernel, dim3(5120), dim3(256), 0, stream,
                           X, logits, W1, adj_out, Xp, W1t);
        hipLaunchKernelGGL(dag_gemm_kernel, dim3(8192), dim3(256), 0, stream,
                           Xp, W1t, b1, W2, b2, outT);
        hipLaunchKernelGGL(transpose_kernel, dim3((BB / 64) * (VV / 64)), dim3(256), 0, stream,
                           outT, out);
    } else {
        hipLaunchKernelGGL(adj_kernel, dim3((VV * VV) / 256), dim3(256), 0, stream,
                           logits, adj_out);
        hipLaunchKernelGGL(fallback_kernel, dim3(VV * (BB / 256)), dim3(256), 0, stream,
                           X, logits, W1, b1, W2, b2, out);
    }
}

// Round 9
// 280.134 us; speedup vs baseline: 1.8468x; 1.1295x over previous
//
#include <hip/hip_runtime.h>
#include <hip/hip_bf16.h>
#include <stdint.h>

// Problem constants (B=4096, V=512, H=64)
#define BB 4096
#define VV 512
#define HH 64

typedef short bf16x8 __attribute__((ext_vector_type(8)));
typedef float floatx4 __attribute__((ext_vector_type(4)));
typedef unsigned short ushort8 __attribute__((ext_vector_type(8)));

typedef const __attribute__((address_space(1))) void g_void;
typedef __attribute__((address_space(3))) void l_void;

__device__ __forceinline__ void gload_lds16(const void* g, void* l) {
    __builtin_amdgcn_global_load_lds((g_void*)g, (l_void*)l, 16, 0, 0);
}

__device__ __forceinline__ unsigned short f2bf_rne(float f) {
    unsigned int u = __float_as_uint(f);
    u += 0x7FFFu + ((u >> 16) & 1u);   // round-to-nearest-even
    return (unsigned short)(u >> 16);
}

// ---------------------------------------------------------------- adj only
__global__ __launch_bounds__(256) void adj_kernel(const float* __restrict__ logits,
                                                  float* __restrict__ adj_out) {
    int idx = blockIdx.x * 256 + threadIdx.x;
    int v = idx >> 9, u = idx & (VV - 1);
    adj_out[idx] = (logits[idx] > 0.0f && v != u) ? 1.0f : 0.0f;
}

// ---------------------------------------------------------------- fused prep
// blocks [0, 4096): W1[i][v][h]*adj[v,i] -> bf16 W1t[i][h][v]  (B^T layout)
// blocks [4096, 5120): adj output + X -> packed bf16 Xp
// Xp layout: [rb][ks][mt][lane][8]; lane=quad*16+ln holds
// X[rb*64+mt*16+ln][ks*32+quad*8..+7] => A-frag loads are coalesced 1 KB.
__global__ __launch_bounds__(256) void prep_fused_kernel(
        const float* __restrict__ X, const float* __restrict__ logits,
        const float* __restrict__ W1, float* __restrict__ adj_out,
        unsigned short* __restrict__ Xp, unsigned short* __restrict__ W1t) {
    __shared__ float tile[64][65];   // stride 65: transpose-read conflict-free
    __shared__ float maskv[64];
    int bx = blockIdx.x;
    int t  = threadIdx.x;
    if (bx < 4096) {
        int i  = bx >> 3;
        int v0 = (bx & 7) << 6;
        if (t < 64) {
            int v = v0 + t;
            maskv[t] = (logits[(size_t)v * VV + i] > 0.0f && v != i) ? 1.0f : 0.0f;
        }
        // float4 global loads; scalar LDS writes at stride 65 (2-way, free).
        const float4* src4 = (const float4*)(W1 + ((size_t)i * VV + v0) * HH);
        #pragma unroll
        for (int jj = 0; jj < 4; ++jj) {
            int c  = jj * 256 + t;         // float4 index in [0, 4096)
            int vr = c >> 4, h4 = c & 15;
            float4 w = src4[c];
            tile[vr][h4 * 4 + 0] = w.x;
            tile[vr][h4 * 4 + 1] = w.y;
            tile[vr][h4 * 4 + 2] = w.z;
            tile[vr][h4 * 4 + 3] = w.w;
        }
        __syncthreads();
        unsigned short* dst = W1t + (size_t)i * (HH * VV) + v0;
        #pragma unroll
        for (int j = 0; j < 2; ++j) {
            int c = j * 256 + t;
            int h = c >> 3;
            int vr0 = (c & 7) * 8;
            ushort8 o;
            #pragma unroll
            for (int r = 0; r < 8; ++r)
                o[r] = f2bf_rne(tile[vr0 + r][h] * maskv[vr0 + r]);
            *(ushort8*)&dst[(size_t)h * VV + vr0] = o;
        }
    } else {
        int idx = (bx - 4096) * 256 + t;           // [0, 262144)
        {   // adj: sigmoid(x) > 0.5  <=>  x > 0 ; zero diagonal
            int v = idx >> 9, u = idx & (VV - 1);
            adj_out[idx] = (logits[idx] > 0.0f && v != u) ? 1.0f : 0.0f;
        }
        {   // pack chunk idx (two float4 reads, one 16B store)
            int lane = idx & 63;
            int mt   = (idx >> 6) & 3;
            int ks   = (idx >> 8) & 15;
            int rb   = idx >> 12;
            int row  = rb * 64 + mt * 16 + (lane & 15);
            int k0   = ks * 32 + (lane >> 4) * 8;
            const float4* s4 = (const float4*)(X + (size_t)row * VV + k0);
            float4 a = s4[0], b = s4[1];
            ushort8 o;
            o[0] = f2bf_rne(a.x); o[1] = f2bf_rne(a.y);
            o[2] = f2bf_rne(a.z); o[3] = f2bf_rne(a.w);
            o[4] = f2bf_rne(b.x); o[5] = f2bf_rne(b.y);
            o[6] = f2bf_rne(b.z); o[7] = f2bf_rne(b.w);
            *(ushort8*)(Xp + (size_t)idx * 8) = o;
        }
    }
}

// ---------------------------------------------------------------- main GEMM
// R3-proven body + K-split staging with PER-HALF LANE-CONTIGUOUS layout.
// CRITICAL (m104/m108): global_load_lds writes wave-uniform base + lane*16;
// every staging loop MUST compute lds addr == c*16 with c = j*256 + t.
// Layout: Ws[half][h][s2], s2 in [0,32); byte off = half*32768 + (h*32+s2)*16.
// Swizzle s2 ^ (h&7) stays in-half (low 3 bits).
// Flow: stage half0 -> barrier -> issue half1 -> K-steps 0..7 (half0) ->
// barrier (half1 landed behind compute, drain ~free) -> K-steps 8..15.
__global__ __launch_bounds__(256, 2) void dag_gemm_kernel(
        const unsigned short* __restrict__ Xp,    // packed A frags
        const unsigned short* __restrict__ W1t,   // [V][H][V] bf16 (masked, B^T)
        const float* __restrict__ b1,             // [V][H]
        const float* __restrict__ W2,             // [V][H]
        const float* __restrict__ b2,             // [V]
        float* __restrict__ outT)                 // [V][B] transposed output
{
    __shared__ __align__(16) unsigned short Ws[2 * 16384];  // 64 KB, [half][h][s2]
    __shared__ float Po[256];                               // epilogue gather

    const int t    = threadIdx.x;
    const int wave = t >> 6;
    const int lane = t & 63;
    const int ln   = lane & 15;
    const int quad = lane >> 4;

    const int bx   = blockIdx.x;          // 8192 blocks, i-major (R3 mapping)
    const int i    = bx >> 4;             // 16 consecutive blocks share W1t row i
    const int row0 = (bx & 15) << 8;

    // B-frag fetch: chunk pos (k/8 units) of row h=nt*16+ln, de-swizzled
    auto ldb = [&](int pos, int nt) -> bf16x8 {
        return *(const bf16x8*)&Ws[(pos >> 5) * 16384 + (nt * 16 + ln) * 256 +
                                   (((pos & 31) ^ (ln & 7)) * 8)];
    };

    // wave's packed A stream: 64 KB contiguous, frag(ks,mt) at +(ks*4+mt)*512
    const unsigned short* abase =
        Xp + (size_t)((row0 >> 6) + wave) * (64 * VV) + lane * 8;

    // ---- issue first 3 K-steps of A prefetch (oldest in vmem queue)
    bf16x8 af[4][4];
    #pragma unroll
    for (int s = 0; s < 3; ++s)
        #pragma unroll
        for (int mt = 0; mt < 4; ++mt)
            af[s][mt] = *(const bf16x8*)(abase + (s * 4 + mt) * 512);

    // ---- stage W1t k-half0 (32 KB): lds addr = c*16 (lane-contiguous ✓)
    const unsigned short* wbase = W1t + (size_t)i * (HH * VV);
    #pragma unroll
    for (int j = 0; j < 8; ++j) {
        int c = j * 256 + t;              // [0, 2048)
        int h = c >> 5, s2 = c & 31;
        gload_lds16(wbase + (size_t)h * VV + (size_t)(s2 ^ (h & 7)) * 8,
                    (char*)Ws + c * 16);
    }
    __syncthreads();   // drains: half0 staged + af[0..2] complete

    // ---- issue k-half1 staging NOW; streams in behind K-steps 0..7
    #pragma unroll
    for (int j = 0; j < 8; ++j) {
        int c = j * 256 + t;
        int h = c >> 5, s2 = c & 31;
        gload_lds16(wbase + (size_t)h * VV + (size_t)(32 + (s2 ^ (h & 7))) * 8,
                    (char*)Ws + 32768 + c * 16);   // half1 base + lane-contig ✓
    }

    floatx4 acc[4][4];
    #pragma unroll
    for (int a = 0; a < 4; ++a)
        #pragma unroll
        for (int b = 0; b < 4; ++b)
            acc[a][b] = (floatx4){0.f, 0.f, 0.f, 0.f};

    bf16x8 bq[2][4];
    #pragma unroll
    for (int nt = 0; nt < 4; ++nt)
        bq[0][nt] = ldb(quad, nt);

    // ---- K-steps 0..7 (k in [0,256): half0 only)
    #pragma unroll
    for (int kk = 0; kk < 8; ++kk) {
        #pragma unroll
        for (int mt = 0; mt < 4; ++mt)     // A prefetch for step kk+3
            af[(kk + 3) & 3][mt] =
                *(const bf16x8*)(abase + ((kk + 3) * 4 + mt) * 512);
        if (kk < 7) {                      // B prefetch for step kk+1 (half0)
            #pragma unroll
            for (int nt = 0; nt < 4; ++nt)
                bq[(kk + 1) & 1][nt] = ldb((kk + 1) * 4 + quad, nt);
        }
        #pragma unroll
        for (int mt = 0; mt < 4; ++mt)
            #pragma unroll
            for (int nt = 0; nt < 4; ++nt)
                acc[mt][nt] = __builtin_amdgcn_mfma_f32_16x16x32_bf16(
                    af[kk & 3][mt], bq[kk & 1][nt], acc[mt][nt], 0, 0, 0);
    }

    __syncthreads();   // half1 landed long ago (issued before steps 0..7)

    // B frags for step 8 (first half1 access)
    #pragma unroll
    for (int nt = 0; nt < 4; ++nt)
        bq[0][nt] = ldb(32 + quad, nt);

    // ---- K-steps 8..15 (k in [256,512): half1)
    #pragma unroll
    for (int kk = 8; kk < 16; ++kk) {
        if (kk < 13) {
            #pragma unroll
            for (int mt = 0; mt < 4; ++mt)
                af[(kk + 3) & 3][mt] =
                    *(const bf16x8*)(abase + ((kk + 3) * 4 + mt) * 512);
        }
        if (kk < 15) {
            #pragma unroll
            for (int nt = 0; nt < 4; ++nt)
                bq[(kk + 1) & 1][nt] = ldb((kk + 1) * 4 + quad, nt);
        }
        #pragma unroll
        for (int mt = 0; mt < 4; ++mt)
            #pragma unroll
            for (int nt = 0; nt < 4; ++nt)
                acc[mt][nt] = __builtin_amdgcn_mfma_f32_16x16x32_bf16(
                    af[kk & 3][mt], bq[kk & 1][nt], acc[mt][nt], 0, 0, 0);
    }

    // ---- fused epilogue: relu(acc + b1) . W2 + b2, fp32; gather via LDS,
    //      then coalesced 256B-per-wave stores to outT[i][rows]
    float b1v[4], w2v[4];
    #pragma unroll
    for (int nt = 0; nt < 4; ++nt) {
        b1v[nt] = b1[i * HH + nt * 16 + ln];
        w2v[nt] = W2[i * HH + nt * 16 + ln];
    }
    const float b2i = b2[i];
    #pragma unroll
    for (int mt = 0; mt < 4; ++mt) {
        #pragma unroll
        for (int r = 0; r < 4; ++r) {
            float p = 0.f;
            #pragma unroll
            for (int nt = 0; nt < 4; ++nt) {
                float hv = acc[mt][nt][r] + b1v[nt];   // C/D: row=quad*4+r, col=nt*16+ln
                hv = hv > 0.f ? hv : 0.f;
                p += hv * w2v[nt];
            }
            p += __shfl_xor(p, 8);
            p += __shfl_xor(p, 4);
            p += __shfl_xor(p, 2);
            p += __shfl_xor(p, 1);
            if (ln == 0)
                Po[wave * 64 + mt * 16 + quad * 4 + r] = p + b2i;
        }
    }
    __syncthreads();
    outT[(size_t)i * BB + row0 + wave * 64 + lane] = Po[wave * 64 + lane];
}

// ------------------------------------------- outT[V][B] -> out[B][V] transpose
__global__ __launch_bounds__(256) void transpose_kernel(const float* __restrict__ outT,
                                                        float* __restrict__ out) {
    __shared__ float tile[64][65];
    int i0 = (blockIdx.x & 7) * 64;
    int r0 = (blockIdx.x >> 3) * 64;
    int t  = threadIdx.x;
    #pragma unroll
    for (int j = 0; j < 16; ++j) {
        int idx = j * 256 + t;
        int ii = idx >> 6, rr = idx & 63;
        tile[ii][rr] = outT[(size_t)(i0 + ii) * BB + r0 + rr];
    }
    __syncthreads();
    #pragma unroll
    for (int j = 0; j < 16; ++j) {
        int idx = j * 256 + t;
        int rr = idx >> 6, ii = idx & 63;
        out[(size_t)(r0 + rr) * VV + i0 + ii] = tile[ii][rr];
    }
}

// ----------------------------- fallback (no workspace): fp32 vector path
__global__ __launch_bounds__(256) void fallback_kernel(
        const float* __restrict__ X, const float* __restrict__ logits,
        const float* __restrict__ W1, const float* __restrict__ b1,
        const float* __restrict__ W2, const float* __restrict__ b2,
        float* __restrict__ out) {
    __shared__ float Wc[128][64];
    int i   = blockIdx.x & (VV - 1);
    int row = (blockIdx.x >> 9) * 256 + threadIdx.x;
    float acc[64];
    #pragma unroll
    for (int h = 0; h < 64; ++h) acc[h] = 0.f;
    for (int v0 = 0; v0 < VV; v0 += 128) {
        __syncthreads();
        for (int j = 0; j < 32; ++j) {
            int idx = j * 256 + threadIdx.x;
            int vr = idx >> 6, h = idx & 63;
            int v = v0 + vr;
            float m = (logits[(size_t)v * VV + i] > 0.f && v != i) ? 1.f : 0.f;
            Wc[vr][h] = W1[((size_t)i * VV + v) * HH + h] * m;
        }
        __syncthreads();
        for (int vr = 0; vr < 128; ++vr) {
            float xv = X[(size_t)row * VV + v0 + vr];
            #pragma unroll
            for (int h = 0; h < 64; ++h) acc[h] += xv * Wc[vr][h];
        }
    }
    float p = b2[i];
    #pragma unroll
    for (int h = 0; h < 64; ++h) {
        float hv = acc[h] + b1[i * HH + h];
        p += (hv > 0.f ? hv : 0.f) * W2[i * HH + h];
    }
    out[(size_t)row * VV + i] = p;
}

extern "C" void kernel_launch(void* const* d_in, const int* in_sizes, int n_in,
                              void* d_out, int out_size, void* d_ws, size_t ws_size,
                              hipStream_t stream) {
    const float* X      = (const float*)d_in[0];
    const float* logits = (const float*)d_in[1];
    const float* W1     = (const float*)d_in[2];
    const float* b1     = (const float*)d_in[3];
    const float* W2     = (const float*)d_in[4];
    const float* b2     = (const float*)d_in[5];

    float* out     = (float*)d_out;                       // reconstructed [B][V]
    float* adj_out = out + (size_t)BB * VV;               // adj [V][V]

    const size_t xp_bytes   = (size_t)BB * VV * 2;        // 4 MB
    const size_t w1t_bytes  = (size_t)VV * HH * VV * 2;   // 32 MB
    const size_t outt_bytes = (size_t)BB * VV * 4;        // 8 MB
    const size_t need = xp_bytes + w1t_bytes + outt_bytes;

    if (ws_size >= need) {
        unsigned short* Xp   = (unsigned short*)d_ws;
        unsigned short* W1t  = (unsigned short*)((char*)d_ws + xp_bytes);
        float*          outT = (float*)((char*)d_ws + xp_bytes + w1t_bytes);
        hipLaunchKernelGGL(prep_fused_kernel, dim3(5120), dim3(256), 0, stream,
                           X, logits, W1, adj_out, Xp, W1t);
        hipLaunchKernelGGL(dag_gemm_kernel, dim3(8192), dim3(256), 0, stream,
                           Xp, W1t, b1, W2, b2, outT);
        hipLaunchKernelGGL(transpose_kernel, dim3((BB / 64) * (VV / 64)), dim3(256), 0, stream,
                           outT, out);
    } else {
        hipLaunchKernelGGL(adj_kernel, dim3((VV * VV) / 256), dim3(256), 0, stream,
                           logits, adj_out);
        hipLaunchKernelGGL(fallback_kernel, dim3(VV * (BB / 256)), dim3(256), 0, stream,
                           X, logits, W1, b1, W2, b2, out);
    }
}